// Round 2
// baseline (574.140 us; speedup 1.0000x reference)
//
#include <hip/hip_runtime.h>

// Problem dims (fixed by setup_inputs)
#define Nn 200000
#define Dn 256
#define Hn 64
#define Sn 8
#define Mn 100000
#define Bn 4096

// Layer-1 tiling: block = 256 rows x 64 cols, 4 waves, each wave 64x64.
// K chunked by 32; X and W staged in LDS as split bf16 (hi/lo planes).
#define RPB 256
#define KC 32
#define NT 256
#define XS 40   // LDS row stride in shorts (32 data + 8 pad) -> 80B, 16B-aligned, bank-spread
#define WS 40

typedef __attribute__((ext_vector_type(8))) short bf16x8;   // MFMA A/B fragment (4 VGPR)
typedef __attribute__((ext_vector_type(4))) float f32x4;    // MFMA C/D fragment
typedef __attribute__((ext_vector_type(8))) unsigned short u16x8; // 16B LDS write
typedef __attribute__((ext_vector_type(4))) unsigned short u16x4; // 8B LDS write

static __device__ __forceinline__ unsigned short f2bf(float x) {
    unsigned u = __float_as_uint(x);
    return (unsigned short)((u + 0x7fffu + ((u >> 16) & 1u)) >> 16);  // RNE
}
static __device__ __forceinline__ float bf2f(unsigned short h) {
    return __uint_as_float(((unsigned)h) << 16);
}

// d_ws layout: hsum[S][B][H] f32, then cnt[S][B] f32
__global__ __launch_bounds__(NT)
void l1_kernel(const float* __restrict__ nf, const float* __restrict__ W1,
               const float* __restrict__ b1, const int* __restrict__ sub_idx,
               const int* __restrict__ bidx, float* __restrict__ hsum,
               float* __restrict__ cnt)
{
    __shared__ unsigned short Xhi[RPB * XS];   // 20 KB
    __shared__ unsigned short Xlo[RPB * XS];   // 20 KB
    __shared__ unsigned short Whi[Hn * WS];    // 5 KB   (col-major: [col][k])
    __shared__ unsigned short Wlo[Hn * WS];    // 5 KB
    __shared__ int sseg[RPB];                  // 1 KB

    const int s    = blockIdx.y;
    const int m0   = blockIdx.x * RPB;
    const int tid  = threadIdx.x;
    const int lane = tid & 63;
    const int w    = tid >> 6;      // wave 0..3 -> rows 64w..64w+63
    const int qq   = lane >> 4;     // 0..3
    const int r16  = lane & 15;

    // one gathered row per thread
    const int  m    = m0 + tid;
    const bool val  = (m < Mn);
    const int  node = val ? sub_idx[(size_t)s * Mn + m] : 0;
    sseg[tid] = val ? bidx[node] : 0;

    const float* xrow = nf + (size_t)node * Dn;

    // W staging role: col = tid&63 (coalesced global reads), k-quads wq and wq+4
    const int wc = tid & 63;
    const int wq = tid >> 6;

    f32x4 acc[4][4];
#pragma unroll
    for (int mi = 0; mi < 4; ++mi)
#pragma unroll
        for (int ni = 0; ni < 4; ++ni) acc[mi][ni] = (f32x4){0.f, 0.f, 0.f, 0.f};

    for (int kk = 0; kk < Dn; kk += KC) {
        __syncthreads();   // protect previous chunk's LDS reads

        // ---- stage X chunk: thread's own row, 32 floats -> hi/lo bf16 ----
        {
            unsigned short hi[KC], lo[KC];
#pragma unroll
            for (int q4 = 0; q4 < KC / 4; ++q4) {
                float4 v = val ? *(const float4*)(xrow + kk + 4 * q4)
                               : make_float4(0.f, 0.f, 0.f, 0.f);
                float xs[4] = {v.x, v.y, v.z, v.w};
#pragma unroll
                for (int e = 0; e < 4; ++e) {
                    unsigned short h = f2bf(xs[e]);
                    hi[4 * q4 + e] = h;
                    lo[4 * q4 + e] = f2bf(xs[e] - bf2f(h));
                }
            }
#pragma unroll
            for (int v8 = 0; v8 < KC / 8; ++v8) {
                *(u16x8*)&Xhi[tid * XS + 8 * v8] = *(const u16x8*)&hi[8 * v8];
                *(u16x8*)&Xlo[tid * XS + 8 * v8] = *(const u16x8*)&lo[8 * v8];
            }
        }
        // ---- stage W chunk col-major: W_lds[c][k], k contiguous ----
#pragma unroll
        for (int h2 = 0; h2 < 2; ++h2) {
            const int kq = wq + 4 * h2;          // k-quad 0..7
            unsigned short whi[4], wlo[4];
#pragma unroll
            for (int i = 0; i < 4; ++i) {
                float wv = W1[((size_t)(s * Dn + kk + 4 * kq + i)) * Hn + wc]; // coalesced over wc
                unsigned short h = f2bf(wv);
                whi[i] = h;
                wlo[i] = f2bf(wv - bf2f(h));
            }
            *(u16x4*)&Whi[wc * WS + 4 * kq] = *(const u16x4*)&whi[0];
            *(u16x4*)&Wlo[wc * WS + 4 * kq] = *(const u16x4*)&wlo[0];
        }
        __syncthreads();

        // ---- fragments + MFMA: A[row=lane&15][k=8*(lane>>4)+j] contiguous-k ----
        bf16x8 ah[4], al[4];
#pragma unroll
        for (int mi = 0; mi < 4; ++mi) {
            const int rb = (64 * w + 16 * mi + r16) * XS + 8 * qq;
            ah[mi] = *(const bf16x8*)&Xhi[rb];
            al[mi] = *(const bf16x8*)&Xlo[rb];
        }
#pragma unroll
        for (int ni = 0; ni < 4; ++ni) {
            const int cb = (16 * ni + r16) * WS + 8 * qq;
            bf16x8 bh = *(const bf16x8*)&Whi[cb];
            bf16x8 bl = *(const bf16x8*)&Wlo[cb];
#pragma unroll
            for (int mi = 0; mi < 4; ++mi) {
                acc[mi][ni] = __builtin_amdgcn_mfma_f32_16x16x32_bf16(ah[mi], bh, acc[mi][ni], 0, 0, 0);
                acc[mi][ni] = __builtin_amdgcn_mfma_f32_16x16x32_bf16(ah[mi], bl, acc[mi][ni], 0, 0, 0);
                acc[mi][ni] = __builtin_amdgcn_mfma_f32_16x16x32_bf16(al[mi], bh, acc[mi][ni], 0, 0, 0);
            }
        }
    }

    // ---- epilogue: bias + relu + atomic scatter ----
    float bcol[4];
#pragma unroll
    for (int ni = 0; ni < 4; ++ni) bcol[ni] = b1[s * Hn + 16 * ni + r16];

#pragma unroll
    for (int mi = 0; mi < 4; ++mi) {
#pragma unroll
        for (int r = 0; r < 4; ++r) {
            const int row = 64 * w + 16 * mi + 4 * qq + r;   // D row = (lane>>4)*4 + reg
            const int mg  = m0 + row;
            if (mg >= Mn) continue;
            const int sg = sseg[row];
            float* dst = hsum + ((size_t)(s * Bn + sg)) * Hn;
#pragma unroll
            for (int ni = 0; ni < 4; ++ni) {
                float v = fmaxf(acc[mi][ni][r] + bcol[ni], 0.f);
                atomicAdd(dst + 16 * ni + r16, v);
            }
        }
    }
    if (val) atomicAdd(cnt + s * Bn + sseg[tid], 1.0f);
}

// out[b][s*H + c] = sum_j hsum[s][b][j] * W2[s][j][c] + cnt[s][b] * b2[s][c]
__global__ __launch_bounds__(256)
void l2_kernel(const float* __restrict__ hsum, const float* __restrict__ cnt,
               const float* __restrict__ W2, const float* __restrict__ b2,
               float* __restrict__ out)
{
    const int wid  = (int)((blockIdx.x * blockDim.x + threadIdx.x) >> 6);
    const int lane = threadIdx.x & 63;
    if (wid >= Sn * Bn) return;
    const int s = wid >> 12;          // Bn = 4096
    const int b = wid & (Bn - 1);

    float hv = hsum[(size_t)wid * Hn + lane];     // coalesced row load
    const float* w2 = W2 + (size_t)s * Hn * Hn + lane;

    float acc = 0.f;
#pragma unroll 8
    for (int jj = 0; jj < Hn; ++jj) {
        float x = __shfl(hv, jj);                 // wave64 broadcast
        acc = fmaf(x, w2[(size_t)jj * Hn], acc);
    }
    float c = cnt[wid];
    float v = acc + c * b2[s * Hn + lane];
    out[(size_t)b * (Sn * Hn) + s * Hn + lane] = v;
}

extern "C" void kernel_launch(void* const* d_in, const int* in_sizes, int n_in,
                              void* d_out, int out_size, void* d_ws, size_t ws_size,
                              hipStream_t stream)
{
    const float* nf   = (const float*)d_in[0];  // node_features [N,D]
    const float* W1   = (const float*)d_in[1];  // [S,D,H]
    const float* b1   = (const float*)d_in[2];  // [S,H]
    const float* W2   = (const float*)d_in[3];  // [S,H,H]
    const float* b2   = (const float*)d_in[4];  // [S,H]
    const int*   sidx = (const int*)d_in[5];    // [S,M]
    const int*   bidx = (const int*)d_in[6];    // [N]
    float* out = (float*)d_out;

    float* hsum = (float*)d_ws;                       // [S*B*H]
    float* cnt  = hsum + (size_t)Sn * Bn * Hn;        // [S*B]

    // ws is re-poisoned to 0xAA before every timed call -> zero our accumulators
    hipMemsetAsync(d_ws, 0, ((size_t)Sn * Bn * Hn + (size_t)Sn * Bn) * sizeof(float),
                   stream);

    dim3 g1((Mn + RPB - 1) / RPB, Sn);   // 391 x 8 blocks
    l1_kernel<<<g1, NT, 0, stream>>>(nf, W1, b1, sidx, bidx, hsum, cnt);

    const int rows    = Sn * Bn;                       // 32768 output rows
    const int blocks2 = (rows * 64 + 255) / 256;       // 8192 blocks
    l2_kernel<<<blocks2, 256, 0, stream>>>(hsum, cnt, W2, b2, out);
}

// Round 3
// 536.204 us; speedup vs baseline: 1.0707x; 1.0707x over previous
//
#include <hip/hip_runtime.h>

// Problem dims (fixed by setup_inputs)
#define Nn 200000
#define Dn 256
#define Hn 64
#define Sn 8
#define Mn 100000
#define Bn 4096

// Layer-1 tiling: block = 256 rows x 64 cols, 4 waves, each wave 64x64.
// K chunked by 32; X and W staged in LDS as split bf16 (hi/lo planes).
#define RPB 256
#define KC 32
#define NT 256
#define XS 40   // LDS row stride in shorts (80B): r*20+4q mod 32 hits all banks, 2-way max (free)
#define WS 40

typedef __attribute__((ext_vector_type(8))) short bf16x8;   // MFMA A/B fragment (4 VGPR)
typedef __attribute__((ext_vector_type(4))) float f32x4;    // MFMA C/D fragment

// Truncation-based split: x ~= hi + lo, both bf16, packed pairwise into u32.
// err(hi) <= 2^-8 |x|, err(hi+lo) <= 2^-16 |x|; dropped lo*lo products ~2^-16.
static __device__ __forceinline__ void split2(float a, float b,
                                              unsigned& h, unsigned& l) {
    unsigned ua = __float_as_uint(a), ub = __float_as_uint(b);
    unsigned ha = ua & 0xFFFF0000u, hb = ub & 0xFFFF0000u;
    float la = a - __uint_as_float(ha);
    float lb = b - __uint_as_float(hb);
    h = (ua >> 16) | hb;
    l = (__float_as_uint(la) >> 16) | (__float_as_uint(lb) & 0xFFFF0000u);
}

// d_ws layout: hsum[S][B][H] f32, then cnt[S][B] f32
__global__ __launch_bounds__(NT, 3)
void l1_kernel(const float* __restrict__ nf, const float* __restrict__ W1,
               const float* __restrict__ b1, const int* __restrict__ sub_idx,
               const int* __restrict__ bidx, float* __restrict__ hsum,
               float* __restrict__ cnt)
{
    __shared__ __align__(16) unsigned short Xhi[RPB * XS];   // 20 KB
    __shared__ __align__(16) unsigned short Xlo[RPB * XS];   // 20 KB
    __shared__ __align__(16) unsigned short Whi[Hn * WS];    // 5 KB   ([col][k])
    __shared__ __align__(16) unsigned short Wlo[Hn * WS];    // 5 KB
    __shared__ unsigned short sseg[RPB];                     // 0.5 KB

    const int s    = blockIdx.y;
    const int m0   = blockIdx.x * RPB;
    const int tid  = threadIdx.x;
    const int lane = tid & 63;
    const int w    = tid >> 6;      // wave 0..3 -> rows 64w..64w+63
    const int qq   = lane >> 4;     // 0..3 (k-oct)
    const int r16  = lane & 15;

    // one gathered row per thread
    const int  m    = m0 + tid;
    const bool val  = (m < Mn);
    const int  node = val ? sub_idx[(size_t)s * Mn + m] : 0;
    sseg[tid] = (unsigned short)(val ? bidx[node] : 0);

    const float* xrow = nf + (size_t)node * Dn;

    // W staging role: col = tid&63, k-oct = tid>>6 (8 contiguous k per thread)
    const int wc = tid & 63;
    const int wq = tid >> 6;

    f32x4 acc[4][4];
#pragma unroll
    for (int mi = 0; mi < 4; ++mi)
#pragma unroll
        for (int ni = 0; ni < 4; ++ni) acc[mi][ni] = (f32x4){0.f, 0.f, 0.f, 0.f};

    // prefetch registers (fp32; converted at store time)
    float fx[8 * 4];   // 32 floats of own row chunk (8 float4)
    float fw[8];       // 8 strided W elems

    // ---- prefetch chunk 0 ----
    {
        const float4* xp = (const float4*)xrow;
#pragma unroll
        for (int v = 0; v < 8; ++v) *(float4*)&fx[4 * v] = xp[v];
        const float* wp = W1 + ((size_t)(s * Dn + 8 * wq)) * Hn + wc;
#pragma unroll
        for (int i = 0; i < 8; ++i) fw[i] = wp[(size_t)i * Hn];
    }

    for (int c = 0; c < Dn / KC; ++c) {
        __syncthreads();   // WAR: all waves done reading previous chunk's LDS

        // ---- convert + store chunk c (from prefetch regs) ----
#pragma unroll
        for (int v = 0; v < 4; ++v) {     // 8 elems per v
            unsigned h[4], l[4];
#pragma unroll
            for (int j = 0; j < 4; ++j)
                split2(fx[8 * v + 2 * j], fx[8 * v + 2 * j + 1], h[j], l[j]);
            *(uint4*)&Xhi[tid * XS + 8 * v] = make_uint4(h[0], h[1], h[2], h[3]);
            *(uint4*)&Xlo[tid * XS + 8 * v] = make_uint4(l[0], l[1], l[2], l[3]);
        }
        {
            unsigned h[4], l[4];
#pragma unroll
            for (int j = 0; j < 4; ++j) split2(fw[2 * j], fw[2 * j + 1], h[j], l[j]);
            *(uint4*)&Whi[wc * WS + 8 * wq] = make_uint4(h[0], h[1], h[2], h[3]);
            *(uint4*)&Wlo[wc * WS + 8 * wq] = make_uint4(l[0], l[1], l[2], l[3]);
        }
        __syncthreads();   // LDS visible to all waves

        // ---- prefetch chunk c+1 (in flight during MFMA phase) ----
        if (c + 1 < Dn / KC) {
            const int kk = (c + 1) * KC;
            const float4* xp = (const float4*)(xrow + kk);
#pragma unroll
            for (int v = 0; v < 8; ++v) *(float4*)&fx[4 * v] = xp[v];
            const float* wp = W1 + ((size_t)(s * Dn + kk + 8 * wq)) * Hn + wc;
#pragma unroll
            for (int i = 0; i < 8; ++i) fw[i] = wp[(size_t)i * Hn];
        }

        // ---- fragments + MFMA: A[row=lane&15][k=8*(lane>>4)+j] contiguous-k ----
        bf16x8 ah[4], al[4];
#pragma unroll
        for (int mi = 0; mi < 4; ++mi) {
            const int rb = (64 * w + 16 * mi + r16) * XS + 8 * qq;
            ah[mi] = *(const bf16x8*)&Xhi[rb];
            al[mi] = *(const bf16x8*)&Xlo[rb];
        }
#pragma unroll
        for (int ni = 0; ni < 4; ++ni) {
            const int cb = (16 * ni + r16) * WS + 8 * qq;
            bf16x8 bh = *(const bf16x8*)&Whi[cb];
            bf16x8 bl = *(const bf16x8*)&Wlo[cb];
#pragma unroll
            for (int mi = 0; mi < 4; ++mi)
                acc[mi][ni] = __builtin_amdgcn_mfma_f32_16x16x32_bf16(ah[mi], bh, acc[mi][ni], 0, 0, 0);
#pragma unroll
            for (int mi = 0; mi < 4; ++mi)
                acc[mi][ni] = __builtin_amdgcn_mfma_f32_16x16x32_bf16(ah[mi], bl, acc[mi][ni], 0, 0, 0);
#pragma unroll
            for (int mi = 0; mi < 4; ++mi)
                acc[mi][ni] = __builtin_amdgcn_mfma_f32_16x16x32_bf16(al[mi], bh, acc[mi][ni], 0, 0, 0);
        }
    }

    // ---- epilogue: bias + relu + atomic scatter ----
    float bcol[4];
#pragma unroll
    for (int ni = 0; ni < 4; ++ni) bcol[ni] = b1[s * Hn + 16 * ni + r16];

#pragma unroll
    for (int mi = 0; mi < 4; ++mi) {
#pragma unroll
        for (int r = 0; r < 4; ++r) {
            const int row = 64 * w + 16 * mi + 4 * qq + r;   // D row = (lane>>4)*4 + reg
            const int mg  = m0 + row;
            if (mg >= Mn) continue;
            const int sg = sseg[row];
            float* dst = hsum + ((size_t)(s * Bn + sg)) * Hn;
#pragma unroll
            for (int ni = 0; ni < 4; ++ni) {
                float v = fmaxf(acc[mi][ni][r] + bcol[ni], 0.f);
                atomicAdd(dst + 16 * ni + r16, v);
            }
        }
    }
    if (val) atomicAdd(cnt + s * Bn + sseg[tid], 1.0f);
}

// out[b][s*H + c] = sum_j hsum[s][b][j] * W2[s][j][c] + cnt[s][b] * b2[s][c]
// Block: 256 threads, one s, 64 consecutive b-rows. W2[s] cached in LDS.
__global__ __launch_bounds__(256)
void l2_kernel(const float* __restrict__ hsum, const float* __restrict__ cnt,
               const float* __restrict__ W2, const float* __restrict__ b2,
               float* __restrict__ out)
{
    __shared__ float W2s[Hn * Hn];   // 16 KB
    const int s    = blockIdx.y;
    const int b0   = blockIdx.x * 64;
    const int tid  = threadIdx.x;
    const int lane = tid & 63;
    const int w    = tid >> 6;

    const float* w2g = W2 + (size_t)s * Hn * Hn;
#pragma unroll
    for (int i = 0; i < 4; ++i)
        ((float4*)W2s)[tid + 256 * i] = ((const float4*)w2g)[tid + 256 * i];
    __syncthreads();

    const float b2v = b2[s * Hn + lane];

#pragma unroll
    for (int g = 0; g < 4; ++g) {
        const int rb = b0 + w * 16 + g * 4;     // 4 rows per group (ILP)
        float hv[4], ct[4], acc[4];
#pragma unroll
        for (int i = 0; i < 4; ++i) {
            const size_t rr = (size_t)s * Bn + rb + i;
            hv[i]  = hsum[rr * Hn + lane];
            ct[i]  = cnt[rr];
            acc[i] = 0.f;
        }
#pragma unroll 8
        for (int j = 0; j < Hn; ++j) {
            float wv = W2s[j * Hn + lane];      // stride-1 over lanes: conflict-free
#pragma unroll
            for (int i = 0; i < 4; ++i)
                acc[i] = fmaf(__shfl(hv[i], j), wv, acc[i]);
        }
#pragma unroll
        for (int i = 0; i < 4; ++i)
            out[(size_t)(rb + i) * (Sn * Hn) + s * Hn + lane] = acc[i] + ct[i] * b2v;
    }
}

extern "C" void kernel_launch(void* const* d_in, const int* in_sizes, int n_in,
                              void* d_out, int out_size, void* d_ws, size_t ws_size,
                              hipStream_t stream)
{
    const float* nf   = (const float*)d_in[0];  // node_features [N,D]
    const float* W1   = (const float*)d_in[1];  // [S,D,H]
    const float* b1   = (const float*)d_in[2];  // [S,H]
    const float* W2   = (const float*)d_in[3];  // [S,H,H]
    const float* b2   = (const float*)d_in[4];  // [S,H]
    const int*   sidx = (const int*)d_in[5];    // [S,M]
    const int*   bidx = (const int*)d_in[6];    // [N]
    float* out = (float*)d_out;

    float* hsum = (float*)d_ws;                       // [S*B*H]
    float* cnt  = hsum + (size_t)Sn * Bn * Hn;        // [S*B]

    // ws is re-poisoned to 0xAA before every timed call -> zero our accumulators
    hipMemsetAsync(d_ws, 0, ((size_t)Sn * Bn * Hn + (size_t)Sn * Bn) * sizeof(float),
                   stream);

    dim3 g1((Mn + RPB - 1) / RPB, Sn);   // 391 x 8 blocks
    l1_kernel<<<g1, NT, 0, stream>>>(nf, W1, b1, sidx, bidx, hsum, cnt);

    dim3 g2(Bn / 64, Sn);                // 64 x 8 blocks
    l2_kernel<<<g2, 256, 0, stream>>>(hsum, cnt, W2, b2, out);
}